// Round 3
// baseline (444.723 us; speedup 1.0000x reference)
//
#include <hip/hip_runtime.h>
#include <hip/hip_bf16.h>
#include <math.h>

#define T_TOKENS 2048
#define DMODEL   1024
#define HID      4096
#define NEXP     8
#define MAX_TILES 64   // M=64 granularity: worst case 32 + 7 slack

typedef float  f32x4  __attribute__((ext_vector_type(4)));
typedef short  bf16x8 __attribute__((ext_vector_type(8)));
typedef unsigned short u16x8 __attribute__((ext_vector_type(8)));

__device__ __forceinline__ unsigned short f2bf(float f) {
    union { float f; unsigned u; } v; v.f = f;
    unsigned u = v.u;
    unsigned r = (u + 0x7FFFu + ((u >> 16) & 1u)) >> 16;   // RNE
    return (unsigned short)r;
}

__device__ __forceinline__ void async_copy16(const void* g, void* l) {
    __builtin_amdgcn_global_load_lds(
        (const __attribute__((address_space(1))) void*)g,
        (__attribute__((address_space(3))) void*)l,
        16, 0, 0);
}

// exact-GELU via A&S 7.1.26 erf (max abs err 1.5e-7 — invisible in bf16)
__device__ __forceinline__ float gelu_f(float v) {
    float z = fabsf(v) * 0.70710678118654752f;
    float t = 1.f / (1.f + 0.3275911f * z);
    float poly = t * (0.254829592f + t * (-0.284496736f + t * (1.421413741f
               + t * (-1.453152027f + t * 1.061405429f))));
    float erfv = 1.f - poly * __expf(-z * z);
    erfv = copysignf(erfv, v);
    return 0.5f * v * (1.f + erfv);
}

// ---------------- router ---------------------------------------------------
__global__ void router_kernel(const float* __restrict__ x, const float* __restrict__ Wr,
                              int* counts, int* expert_of, int* slot_of, float* wt_of) {
    int t = blockIdx.x;
    int lane = threadIdx.x;
    const float* xr = x + (size_t)t * DMODEL;
    float p[NEXP];
#pragma unroll
    for (int e = 0; e < NEXP; ++e) p[e] = 0.f;
    for (int d = lane; d < DMODEL; d += 64) {
        float xv = xr[d];
        const float* wr = Wr + (size_t)d * NEXP;
#pragma unroll
        for (int e = 0; e < NEXP; ++e) p[e] += xv * wr[e];
    }
#pragma unroll
    for (int e = 0; e < NEXP; ++e) {
        for (int off = 32; off > 0; off >>= 1)
            p[e] += __shfl_down(p[e], off, 64);
    }
    if (lane == 0) {
        int i0 = 0; float v0 = p[0];
        for (int e = 1; e < NEXP; ++e) if (p[e] > v0) { v0 = p[e]; i0 = e; }
        float v1 = -INFINITY;
        for (int e = 0; e < NEXP; ++e) if (e != i0 && p[e] > v1) v1 = p[e];
        float w = 1.f / (1.f + expf(v1 - v0));
        expert_of[t] = i0;
        wt_of[t] = w;
        slot_of[t] = atomicAdd(&counts[i0], 1);
    }
}

// ---------------- scan + tile list (M=64) + scatter, single block ----------
__global__ void scan_scatter_kernel(const int* counts, const int* expert_of,
                                    const int* slot_of, int* offsets, int* perm,
                                    int* tileE, int* tileM, int* tileCount) {
    __shared__ int offs[NEXP];
    if (threadIdx.x == 0) {
        int run = 0, tc = 0;
        for (int e = 0; e < NEXP; ++e) {
            offsets[e] = run; offs[e] = run;
            for (int m0 = 0; m0 < counts[e]; m0 += 64) { tileE[tc] = e; tileM[tc] = m0; ++tc; }
            run += counts[e];
        }
        *tileCount = tc;
    }
    __syncthreads();
    for (int t = threadIdx.x; t < T_TOKENS; t += 256)
        perm[offs[expert_of[t]] + slot_of[t]] = t;
}

// ---------------- fp32 [e][K][N] -> bf16 [e][N][K] ------------------------
__global__ __launch_bounds__(256) void convert_transpose_kernel(
    const float* __restrict__ W, unsigned short* __restrict__ WT, int K, int N) {
    int ktiles = K >> 6, ntiles = N >> 6;
    int gid = blockIdx.x;
    int e   = gid / (ktiles * ntiles);
    int r   = gid % (ktiles * ntiles);
    int kt  = r / ntiles, nt = r % ntiles;
    const float* src = W + (size_t)e * K * N + (size_t)(kt * 64) * N + nt * 64;
    unsigned short* dst = WT + (size_t)e * N * K + (size_t)(nt * 64) * K + kt * 64;

    __shared__ unsigned short tile[64][66];
    int tid = threadIdx.x;
    int n4 = (tid & 15) * 4;
    int kk = tid >> 4;
#pragma unroll
    for (int p = 0; p < 4; ++p) {
        int k = kk + p * 16;
        float4 v = *(const float4*)(src + (size_t)k * N + n4);
        tile[n4 + 0][k] = f2bf(v.x);
        tile[n4 + 1][k] = f2bf(v.y);
        tile[n4 + 2][k] = f2bf(v.z);
        tile[n4 + 3][k] = f2bf(v.w);
    }
    __syncthreads();
    int n = tid >> 2, ks = (tid & 3) * 16;
    unsigned short tmp[16];
#pragma unroll
    for (int i = 0; i < 16; ++i) tmp[i] = tile[n][ks + i];
    *(u16x8*)(dst + (size_t)n * K + ks)     = *(u16x8*)&tmp[0];
    *(u16x8*)(dst + (size_t)n * K + ks + 8) = *(u16x8*)&tmp[8];
}

__global__ __launch_bounds__(256) void convert_x_kernel(
    const float* __restrict__ x, unsigned short* __restrict__ xbf) {
    int i = (blockIdx.x * 256 + threadIdx.x) * 4;
    float4 v = *(const float4*)(x + i);
    ushort4 b;
    b.x = f2bf(v.x); b.y = f2bf(v.y); b.z = f2bf(v.z); b.w = f2bf(v.w);
    *(ushort4*)(xbf + i) = b;
}

// ---------------- GEMM1: M=64,N=128 tile. H = GELU(Xbf[perm] @ W1T^T) ------
__global__ __launch_bounds__(256, 4) void gemm1_kernel(
    const unsigned short* __restrict__ Xbf, const unsigned short* __restrict__ W1T,
    const int* __restrict__ counts, const int* __restrict__ offsets,
    const int* __restrict__ perm, const int* __restrict__ tileE,
    const int* __restrict__ tileM, const int* __restrict__ tileCount,
    unsigned short* __restrict__ H) {

    const int NT = HID / 128;                 // 32
    int tile = blockIdx.x / NT;
    int nt   = blockIdx.x % NT;
    if (tile >= *tileCount) return;
    int e = tileE[tile], m0 = tileM[tile];
    int rows_e = counts[e], base = offsets[e];
    int n0 = nt * 128;

    __shared__ unsigned short Alds[64 * 64];    // [m][k]
    __shared__ unsigned short Blds[128 * 64];   // [n][k]

    int tid  = threadIdx.x;
    int lane = tid & 63;
    int wid  = tid >> 6;
    int wm = wid >> 1, wn = wid & 1;

    // staging addresses: A: 512 chunks (2/thread), B: 1024 chunks (4/thread)
    const unsigned short* ag[2]; unsigned short* al[2];
    const unsigned short* bg[4]; unsigned short* bl[4];
#pragma unroll
    for (int p = 0; p < 2; ++p) {
        int idx = p * 256 + tid;
        int row = idx >> 3, seg = idx & 7;
        int r = m0 + row;
        int tok = perm[base + (r < rows_e ? r : rows_e - 1)];
        ag[p] = Xbf + (size_t)tok * DMODEL + seg * 8;
        al[p] = &Alds[idx * 8];
    }
#pragma unroll
    for (int p = 0; p < 4; ++p) {
        int idx = p * 256 + tid;
        int row = idx >> 3, seg = idx & 7;
        bg[p] = W1T + ((size_t)e * HID + n0 + row) * DMODEL + seg * 8;
        bl[p] = &Blds[idx * 8];
    }

    f32x4 acc[2][4];
#pragma unroll
    for (int i = 0; i < 2; ++i)
#pragma unroll
        for (int j = 0; j < 4; ++j) acc[i][j] = (f32x4){0.f, 0.f, 0.f, 0.f};

    for (int k0 = 0; k0 < DMODEL; k0 += 64) {
        __syncthreads();
#pragma unroll
        for (int p = 0; p < 2; ++p) async_copy16(ag[p] + k0, al[p]);
#pragma unroll
        for (int p = 0; p < 4; ++p) async_copy16(bg[p] + k0, bl[p]);
        __syncthreads();
#pragma unroll
        for (int ks = 0; ks < 2; ++ks) {
            int kq = ks * 32 + (lane >> 4) * 8;
            bf16x8 af[2], bfr[4];
#pragma unroll
            for (int i = 0; i < 2; ++i) {
                int m = wm * 32 + i * 16 + (lane & 15);
                af[i] = *(const bf16x8*)&Alds[m * 64 + kq];
            }
#pragma unroll
            for (int j = 0; j < 4; ++j) {
                int n = wn * 64 + j * 16 + (lane & 15);
                bfr[j] = *(const bf16x8*)&Blds[n * 64 + kq];
            }
#pragma unroll
            for (int i = 0; i < 2; ++i)
#pragma unroll
                for (int j = 0; j < 4; ++j)
                    acc[i][j] = __builtin_amdgcn_mfma_f32_16x16x32_bf16(af[i], bfr[j], acc[i][j], 0, 0, 0);
        }
    }

    int quad = lane >> 4, col = lane & 15;
#pragma unroll
    for (int i = 0; i < 2; ++i)
#pragma unroll
        for (int j = 0; j < 4; ++j)
#pragma unroll
            for (int r = 0; r < 4; ++r) {
                int ml = wm * 32 + i * 16 + quad * 4 + r;
                if (m0 + ml < rows_e) {
                    int n = n0 + wn * 64 + j * 16 + col;
                    H[(size_t)(base + m0 + ml) * HID + n] = f2bf(gelu_f(acc[i][j][r]));
                }
            }
}

// ---------------- GEMM2: M=64,N=128,SK=2 -> partials (plain stores) --------
__global__ __launch_bounds__(256, 4) void gemm2_kernel(
    const unsigned short* __restrict__ H, const unsigned short* __restrict__ W2T,
    const int* __restrict__ counts, const int* __restrict__ offsets,
    const int* __restrict__ perm, const float* __restrict__ wt_of,
    const int* __restrict__ tileE, const int* __restrict__ tileM,
    const int* __restrict__ tileCount, float* __restrict__ part) {

    const int NT = DMODEL / 128;              // 8
    int tile = blockIdx.x / (NT * 2);
    int rem  = blockIdx.x % (NT * 2);
    int nt   = rem >> 1;
    int sk   = rem & 1;
    if (tile >= *tileCount) return;
    int e = tileE[tile], m0 = tileM[tile];
    int rows_e = counts[e], base = offsets[e];
    int n0 = nt * 128;
    int kbeg = sk * (HID / 2), kend = kbeg + (HID / 2);

    __shared__ unsigned short Alds[64 * 64];
    __shared__ unsigned short Blds[128 * 64];
    __shared__ float rowW[64];

    int tid  = threadIdx.x;
    int lane = tid & 63;
    int wid  = tid >> 6;
    int wm = wid >> 1, wn = wid & 1;

    if (tid < 64) {
        int r = m0 + tid;
        rowW[tid] = (r < rows_e) ? wt_of[perm[base + r]] : 0.f;
    }

    const unsigned short* ag[2]; unsigned short* al[2];
    const unsigned short* bg[4]; unsigned short* bl[4];
#pragma unroll
    for (int p = 0; p < 2; ++p) {
        int idx = p * 256 + tid;
        int row = idx >> 3, seg = idx & 7;
        int hr = base + m0 + row;
        if (hr > T_TOKENS - 1) hr = T_TOKENS - 1;
        ag[p] = H + (size_t)hr * HID + seg * 8;
        al[p] = &Alds[idx * 8];
    }
#pragma unroll
    for (int p = 0; p < 4; ++p) {
        int idx = p * 256 + tid;
        int row = idx >> 3, seg = idx & 7;
        bg[p] = W2T + ((size_t)e * DMODEL + n0 + row) * HID + seg * 8;
        bl[p] = &Blds[idx * 8];
    }

    f32x4 acc[2][4];
#pragma unroll
    for (int i = 0; i < 2; ++i)
#pragma unroll
        for (int j = 0; j < 4; ++j) acc[i][j] = (f32x4){0.f, 0.f, 0.f, 0.f};

    for (int k0 = kbeg; k0 < kend; k0 += 64) {
        __syncthreads();
#pragma unroll
        for (int p = 0; p < 2; ++p) async_copy16(ag[p] + k0, al[p]);
#pragma unroll
        for (int p = 0; p < 4; ++p) async_copy16(bg[p] + k0, bl[p]);
        __syncthreads();
#pragma unroll
        for (int ks = 0; ks < 2; ++ks) {
            int kq = ks * 32 + (lane >> 4) * 8;
            bf16x8 af[2], bfr[4];
#pragma unroll
            for (int i = 0; i < 2; ++i) {
                int m = wm * 32 + i * 16 + (lane & 15);
                af[i] = *(const bf16x8*)&Alds[m * 64 + kq];
            }
#pragma unroll
            for (int j = 0; j < 4; ++j) {
                int n = wn * 64 + j * 16 + (lane & 15);
                bfr[j] = *(const bf16x8*)&Blds[n * 64 + kq];
            }
#pragma unroll
            for (int i = 0; i < 2; ++i)
#pragma unroll
                for (int j = 0; j < 4; ++j)
                    acc[i][j] = __builtin_amdgcn_mfma_f32_16x16x32_bf16(af[i], bfr[j], acc[i][j], 0, 0, 0);
        }
    }

    // each (sk, sorted-row, n) written exactly once -> plain stores, no zeroing
    float* dst = part + (size_t)sk * T_TOKENS * DMODEL;
    int quad = lane >> 4, col = lane & 15;
#pragma unroll
    for (int i = 0; i < 2; ++i)
#pragma unroll
        for (int j = 0; j < 4; ++j)
#pragma unroll
            for (int r = 0; r < 4; ++r) {
                int ml = wm * 32 + i * 16 + quad * 4 + r;
                if (m0 + ml < rows_e) {
                    int n = n0 + wn * 64 + j * 16 + col;
                    dst[(size_t)(base + m0 + ml) * DMODEL + n] = rowW[ml] * acc[i][j][r];
                }
            }
}

// ---------------- split-K reduce + scatter to token rows -------------------
__global__ __launch_bounds__(256) void reduce_kernel(
    const float* __restrict__ part, const int* __restrict__ perm,
    float* __restrict__ out) {
    int row = blockIdx.x;                     // sorted row, one block per row
    int tok = perm[row];
    const float4* p0 = (const float4*)(part + (size_t)row * DMODEL);
    const float4* p1 = (const float4*)(part + (size_t)(T_TOKENS + row) * DMODEL);
    float4* o = (float4*)(out + (size_t)tok * DMODEL);
    int c = threadIdx.x;                      // 256 threads x float4 = 1024 floats
    float4 a = p0[c], b = p1[c];
    o[c] = make_float4(a.x + b.x, a.y + b.y, a.z + b.z, a.w + b.w);
}

extern "C" void kernel_launch(void* const* d_in, const int* in_sizes, int n_in,
                              void* d_out, int out_size, void* d_ws, size_t ws_size,
                              hipStream_t stream) {
    const float* x  = (const float*)d_in[0];
    const float* Wr = (const float*)d_in[1];
    const float* W1 = (const float*)d_in[2];
    const float* W2 = (const float*)d_in[3];
    float* out = (float*)d_out;

    char* ws = (char*)d_ws;
    int*   counts    = (int*)(ws);
    int*   offsets   = (int*)(ws + 64);
    int*   tileCount = (int*)(ws + 128);
    int*   tileE     = (int*)(ws + 256);
    int*   tileM     = (int*)(ws + 256 + 4 * MAX_TILES);
    int*   expert_of = (int*)(ws + 1024);
    int*   slot_of   = (int*)(ws + 1024 + 8192);
    float* wt_of     = (float*)(ws + 1024 + 16384);
    int*   perm      = (int*)(ws + 1024 + 24576);
    size_t off = 65536;
    unsigned short* Xbf  = (unsigned short*)(ws + off); off += (size_t)T_TOKENS * DMODEL * 2;   // 4 MB
    unsigned short* Hbuf = (unsigned short*)(ws + off); off += (size_t)T_TOKENS * HID * 2;      // 16 MB
    float*          Part = (float*)(ws + off);          off += (size_t)2 * T_TOKENS * DMODEL * 4; // 16 MB
    unsigned short* W1T  = (unsigned short*)(ws + off); off += (size_t)NEXP * DMODEL * HID * 2; // 64 MB
    unsigned short* W2T  = (unsigned short*)(ws + off);                                          // 64 MB

    hipMemsetAsync(counts, 0, 64, stream);
    router_kernel<<<T_TOKENS, 64, 0, stream>>>(x, Wr, counts, expert_of, slot_of, wt_of);
    scan_scatter_kernel<<<1, 256, 0, stream>>>(counts, expert_of, slot_of,
                                               offsets, perm, tileE, tileM, tileCount);
    convert_x_kernel<<<(T_TOKENS * DMODEL) / 1024, 256, 0, stream>>>(x, Xbf);
    convert_transpose_kernel<<<NEXP * (DMODEL / 64) * (HID / 64), 256, 0, stream>>>(W1, W1T, DMODEL, HID);
    gemm1_kernel<<<MAX_TILES * (HID / 128), 256, 0, stream>>>(
        Xbf, W1T, counts, offsets, perm, tileE, tileM, tileCount, Hbuf);
    convert_transpose_kernel<<<NEXP * (HID / 64) * (DMODEL / 64), 256, 0, stream>>>(W2, W2T, HID, DMODEL);
    gemm2_kernel<<<MAX_TILES * (DMODEL / 128) * 2, 256, 0, stream>>>(
        Hbuf, W2T, counts, offsets, perm, wt_of, tileE, tileM, tileCount, Part);
    reduce_kernel<<<T_TOKENS, 256, 0, stream>>>(Part, perm, out);
}